// Round 6
// baseline (83.824 us; speedup 1.0000x reference)
//
#include <hip/hip_runtime.h>
#include <hip/hip_bf16.h>

#define TV    512
#define TL    64
#define D_    512
#define BKT   64
#define VROWS 64
#define NCHUNK (TV/VROWS)   // 8
#define NKT   (D_/BKT)      // 8

typedef __attribute__((ext_vector_type(8))) short bf16x8;
typedef __attribute__((ext_vector_type(4))) float f32x4;

__global__ __launch_bounds__(256, 4) void chamfer_main(
    const float* __restrict__ vf, const float* __restrict__ lf,
    const float* __restrict__ mv, const float* __restrict__ ml,
    float* __restrict__ pcol, float* __restrict__ psum)
{
  // XCD-aware decode: all 8 chunks of a batch land on the same XCD
  // (XCD = linear_id % 8 on MI355X), so the shared L-slice stays L2-hot.
  const int lin   = blockIdx.x;          // 0..1023
  const int xcd   = lin & 7;
  const int kk    = lin >> 3;            // 0..127
  const int chunk = kk & 7;
  const int b     = ((kk >> 3) << 3) | xcd;   // bijective over 0..127

  const int t     = threadIdx.x;
  const int w     = t >> 6;
  const int lane  = t & 63;
  const int g     = lane >> 4;
  const int c15   = lane & 15;
  const int srow  = t >> 2;              // 0..63  staging row
  const int skc   = (t & 3) * 2;         // 0,2,4,6 staging k-chunk (x8 floats)

  // double-buffered swizzled bf16 tiles: one barrier per K-tile
  __shared__ __align__(16) short lv[2][VROWS * BKT];  // 2 x 8 KiB
  __shared__ __align__(16) short ll[2][TL * BKT];     // 2 x 8 KiB
  __shared__ float normv_s[VROWS];
  __shared__ float norml_s[TL];
  __shared__ float mvs[VROWS];
  __shared__ float mls[TL];
  __shared__ float wavecol[4][TL];
  __shared__ float wavesum[4];

  const int v0 = chunk * VROWS;
  const float* vbase = vf + ((size_t)b * TV + v0) * D_;
  const float* lbase = lf + (size_t)b * TL * D_;
  const float* vrow = vbase + (size_t)srow * D_ + skc * 8;
  const float* lrow = lbase + (size_t)srow * D_ + skc * 8;

  if (t < VROWS)                mvs[t]        = mv[(size_t)b * TV + v0 + t];
  else if (t < VROWS + TL)      mls[t - VROWS] = ml[(size_t)b * TL + (t - VROWS)];

  f32x4 acc[4];
  #pragma unroll
  for (int n = 0; n < 4; n++) acc[n] = (f32x4){0.f, 0.f, 0.f, 0.f};

  float nvacc = 0.f;   // staging-layout partial norms (row = t>>2)
  float nlacc = 0.f;

  // two named prefetch register sets (A = even tiles, B = odd tiles)
  float4 vA[4], lA[4], vB[4], lB[4];

#define STAGE_LOAD(VS, LS, KT) do {                                              \
    const float4* sv_ = (const float4*)(vrow + (KT) * BKT);                      \
    const float4* sl_ = (const float4*)(lrow + (KT) * BKT);                      \
    VS[0] = sv_[0]; VS[1] = sv_[1]; VS[2] = sv_[2]; VS[3] = sv_[3];              \
    LS[0] = sl_[0]; LS[1] = sl_[1]; LS[2] = sl_[2]; LS[3] = sl_[3];              \
  } while (0)

#define CVT_STORE(VS, LS, BUF) do {                                              \
    _Pragma("unroll")                                                            \
    for (int h_ = 0; h_ < 2; h_++) {                                             \
      float4 a_ = VS[h_*2], b_ = VS[h_*2+1];                                     \
      nvacc += a_.x*a_.x + a_.y*a_.y + a_.z*a_.z + a_.w*a_.w                     \
             + b_.x*b_.x + b_.y*b_.y + b_.z*b_.z + b_.w*b_.w;                    \
      union { bf16x8 v8; __hip_bfloat162 h[4]; } u_;                             \
      u_.h[0] = __float22bfloat162_rn(make_float2(a_.x, a_.y));                  \
      u_.h[1] = __float22bfloat162_rn(make_float2(a_.z, a_.w));                  \
      u_.h[2] = __float22bfloat162_rn(make_float2(b_.x, b_.y));                  \
      u_.h[3] = __float22bfloat162_rn(make_float2(b_.z, b_.w));                  \
      int off_ = (srow * 128 + (skc + h_) * 16) ^ ((srow & 7) << 4);             \
      *(bf16x8*)((char*)lv[BUF] + off_) = u_.v8;                                 \
      float4 c_ = LS[h_*2], d_ = LS[h_*2+1];                                     \
      nlacc += c_.x*c_.x + c_.y*c_.y + c_.z*c_.z + c_.w*c_.w                     \
             + d_.x*d_.x + d_.y*d_.y + d_.z*d_.z + d_.w*d_.w;                    \
      union { bf16x8 v8; __hip_bfloat162 h[4]; } u2_;                            \
      u2_.h[0] = __float22bfloat162_rn(make_float2(c_.x, c_.y));                 \
      u2_.h[1] = __float22bfloat162_rn(make_float2(c_.z, c_.w));                 \
      u2_.h[2] = __float22bfloat162_rn(make_float2(d_.x, d_.y));                 \
      u2_.h[3] = __float22bfloat162_rn(make_float2(d_.z, d_.w));                 \
      *(bf16x8*)((char*)ll[BUF] + off_) = u2_.v8;                                \
    }                                                                            \
  } while (0)

#define MFMA_TILE(BUF) do {                                                      \
    _Pragma("unroll")                                                            \
    for (int ks_ = 0; ks_ < 2; ks_++) {                                          \
      bf16x8 afr_, bfr_[4];                                                      \
      {                                                                          \
        int row_ = w * 16 + c15;                                                 \
        int off_ = (row_ * 128 + ks_ * 64 + g * 16) ^ ((row_ & 7) << 4);         \
        afr_ = *(const bf16x8*)((const char*)lv[BUF] + off_);                    \
      }                                                                          \
      _Pragma("unroll")                                                          \
      for (int n_ = 0; n_ < 4; n_++) {                                           \
        int row_ = n_ * 16 + c15;                                                \
        int off_ = (row_ * 128 + ks_ * 64 + g * 16) ^ ((row_ & 7) << 4);         \
        bfr_[n_] = *(const bf16x8*)((const char*)ll[BUF] + off_);                \
      }                                                                          \
      _Pragma("unroll")                                                          \
      for (int n_ = 0; n_ < 4; n_++)                                             \
        acc[n_] = __builtin_amdgcn_mfma_f32_16x16x32_bf16(                       \
            afr_, bfr_[n_], acc[n_], 0, 0, 0);                                   \
    }                                                                            \
  } while (0)

  // software pipeline, depth 1, double-buffered LDS, ONE barrier per tile
  STAGE_LOAD(vA, lA, 0);
  CVT_STORE(vA, lA, 0);  STAGE_LOAD(vB, lB, 1);  __syncthreads();  MFMA_TILE(0);
  CVT_STORE(vB, lB, 1);  STAGE_LOAD(vA, lA, 2);  __syncthreads();  MFMA_TILE(1);
  CVT_STORE(vA, lA, 0);  STAGE_LOAD(vB, lB, 3);  __syncthreads();  MFMA_TILE(0);
  CVT_STORE(vB, lB, 1);  STAGE_LOAD(vA, lA, 4);  __syncthreads();  MFMA_TILE(1);
  CVT_STORE(vA, lA, 0);  STAGE_LOAD(vB, lB, 5);  __syncthreads();  MFMA_TILE(0);
  CVT_STORE(vB, lB, 1);  STAGE_LOAD(vA, lA, 6);  __syncthreads();  MFMA_TILE(1);
  CVT_STORE(vA, lA, 0);  STAGE_LOAD(vB, lB, 7);  __syncthreads();  MFMA_TILE(0);
  CVT_STORE(vB, lB, 1);                          __syncthreads();  MFMA_TILE(1);
#undef STAGE_LOAD
#undef CVT_STORE
#undef MFMA_TILE

  // ---- row-norm reductions (4 consecutive lanes share a staging row) ----
  {
    float s = nvacc;
    s += __shfl_xor(s, 1); s += __shfl_xor(s, 2);
    if ((t & 3) == 0) normv_s[t >> 2] = s;
    float s2 = nlacc;
    s2 += __shfl_xor(s2, 1); s2 += __shfl_xor(s2, 2);
    if ((t & 3) == 0) norml_s[t >> 2] = s2;
  }
  __syncthreads();

  // ---- epilogue: pd + masking, row/col mins ----
  const float BIG = 3.0e38f;
  float pdv[4][4];   // [n][j]
  #pragma unroll
  for (int n = 0; n < 4; n++)
    #pragma unroll
    for (int j = 0; j < 4; j++) {
      int row = w * 16 + g * 4 + j;
      int col = n * 16 + c15;
      float pd = normv_s[row] + norml_s[col] - 2.0f * acc[n][j];
      bool valid = (mvs[row] != 0.f) && (mls[col] != 0.f);
      pdv[n][j] = valid ? pd : BIG;
    }

  // row mins (over all 64 cols) -> masked sum over this wave's 16 rows
  float svl = 0.f;
  #pragma unroll
  for (int j = 0; j < 4; j++) {
    float rm = fminf(fminf(pdv[0][j], pdv[1][j]),
                     fminf(pdv[2][j], pdv[3][j]));
    rm = fminf(rm, __shfl_xor(rm, 1));
    rm = fminf(rm, __shfl_xor(rm, 2));
    rm = fminf(rm, __shfl_xor(rm, 4));
    rm = fminf(rm, __shfl_xor(rm, 8));
    int row = w * 16 + g * 4 + j;
    if (c15 == 0 && mvs[row] != 0.f) svl += rm;
  }
  svl += __shfl_xor(svl, 16);
  svl += __shfl_xor(svl, 32);
  if (lane == 0) wavesum[w] = svl;

  // col mins over this wave's 16 rows
  #pragma unroll
  for (int n = 0; n < 4; n++) {
    float cm = fminf(fminf(pdv[n][0], pdv[n][1]),
                     fminf(pdv[n][2], pdv[n][3]));
    cm = fminf(cm, __shfl_xor(cm, 16));
    cm = fminf(cm, __shfl_xor(cm, 32));
    if (g == 0) wavecol[w][n * 16 + c15] = cm;
  }
  __syncthreads();

  if (t < TL) {
    float cm = fminf(fminf(wavecol[0][t], wavecol[1][t]),
                     fminf(wavecol[2][t], wavecol[3][t]));
    pcol[((size_t)b * NCHUNK + chunk) * TL + t] = cm;
  }
  if (t == 0)
    psum[(size_t)b * NCHUNK + chunk] = wavesum[0] + wavesum[1] + wavesum[2] + wavesum[3];
}

__global__ __launch_bounds__(64) void chamfer_fin(
    const float* __restrict__ pcol, const float* __restrict__ psum,
    const float* __restrict__ mv, const float* __restrict__ ml,
    float* __restrict__ out)
{
  int b = blockIdx.x;
  int l = threadIdx.x;
  float cm = pcol[((size_t)b * NCHUNK + 0) * 64 + l];
  #pragma unroll
  for (int i = 1; i < NCHUNK; i++)
    cm = fminf(cm, pcol[((size_t)b * NCHUNK + i) * 64 + l]);
  float mlv = ml[(size_t)b * 64 + l];
  float sl = (mlv != 0.f) ? cm : 0.f;
  float nl = mlv;
  float nv = 0.f;
  #pragma unroll
  for (int i = 0; i < 8; i++) nv += mv[(size_t)b * 512 + l * 8 + i];
  float sv = (l < NCHUNK) ? psum[(size_t)b * NCHUNK + l] : 0.f;
  #pragma unroll
  for (int s = 1; s < 64; s <<= 1) {
    sl += __shfl_xor(sl, s);
    nl += __shfl_xor(nl, s);
    nv += __shfl_xor(nv, s);
    sv += __shfl_xor(sv, s);
  }
  if (l == 0) out[b] = sl / nl + sv / nv;
}

extern "C" void kernel_launch(void* const* d_in, const int* in_sizes, int n_in,
                              void* d_out, int out_size, void* d_ws, size_t ws_size,
                              hipStream_t stream) {
  const float* vf = (const float*)d_in[0];
  const float* lf = (const float*)d_in[1];
  const float* mv = (const float*)d_in[2];
  const float* ml = (const float*)d_in[3];
  float* out  = (float*)d_out;
  float* pcol = (float*)d_ws;                       // [128][8][64]
  float* psum = pcol + 128 * NCHUNK * 64;           // [128][8]
  chamfer_main<<<128 * NCHUNK, 256, 0, stream>>>(vf, lf, mv, ml, pcol, psum);
  chamfer_fin<<<128, 64, 0, stream>>>(pcol, psum, mv, ml, out);
}

// Round 7
// 33.447 us; speedup vs baseline: 2.5062x; 2.5062x over previous
//
#include <hip/hip_runtime.h>
#include <hip/hip_bf16.h>

#define TV    512
#define TL    64
#define D_    512
#define BKT   128
#define VROWS 64
#define NCHUNK (TV/VROWS)   // 8
#define NKT   (D_/BKT)      // 4

typedef __attribute__((ext_vector_type(8))) short bf16x8;
typedef __attribute__((ext_vector_type(4))) float f32x4;

__global__ __launch_bounds__(256, 4) void chamfer_main(
    const float* __restrict__ vf, const float* __restrict__ lf,
    const float* __restrict__ mv, const float* __restrict__ ml,
    float* __restrict__ pcol, float* __restrict__ psum)
{
  // XCD-aware decode: all 8 chunks of a batch land on the same XCD
  // (XCD = linear_id % 8 on MI355X), so the shared L-slice stays L2-hot.
  const int lin   = blockIdx.x;          // 0..1023
  const int xcd   = lin & 7;
  const int kk    = lin >> 3;            // 0..127
  const int chunk = kk & 7;
  const int b     = ((kk >> 3) << 3) | xcd;   // bijective over 0..127

  const int t     = threadIdx.x;
  const int w     = t >> 6;
  const int lane  = t & 63;
  const int g     = lane >> 4;
  const int c15   = lane & 15;

  // single-buffered swizzled bf16 tiles, 64 rows x 128 k each (16 KiB each)
  __shared__ __align__(16) short lv[VROWS * BKT];
  __shared__ __align__(16) short ll[TL * BKT];
  __shared__ float normv_s[VROWS];
  __shared__ float norml_s[TL];
  __shared__ float mvs[VROWS];
  __shared__ float mls[TL];
  __shared__ float wavecol[4][TL];
  __shared__ float wavesum[4];

  const int v0 = chunk * VROWS;
  const float* vbase = vf + ((size_t)b * TV + v0) * D_;
  const float* lbase = lf + (size_t)b * TL * D_;

  if (t < VROWS)                mvs[t]        = mv[(size_t)b * TV + v0 + t];
  else if (t < VROWS + TL)      mls[t - VROWS] = ml[(size_t)b * TL + (t - VROWS)];

  f32x4 acc[4];
  #pragma unroll
  for (int n = 0; n < 4; n++) acc[n] = (f32x4){0.f, 0.f, 0.f, 0.f};

  // per-p row-norm partials (p selects row = p*16 + (t>>4))
  float nvacc[4] = {0.f, 0.f, 0.f, 0.f};
  float nlacc[4] = {0.f, 0.f, 0.f, 0.f};

  for (int kt = 0; kt < NKT; ++kt) {
    // ---- stage V and L tiles (64 rows x 128 k, bf16, swizzled) ----
    // transient registers only: load -> norm -> cvt -> LDS store per p-iter
    #pragma unroll
    for (int p = 0; p < 4; p++) {
      int idx = p * 256 + t;          // 0..1023
      int row = idx >> 4;             // 0..63
      int kc  = idx & 15;             // 0..15 (8-float chunks)
      int off = (row * 256 + kc * 16) ^ ((row & 7) << 4);

      const float4* sv_ = (const float4*)(vbase + (size_t)row * D_ + kt * BKT + kc * 8);
      float4 a = sv_[0], bq = sv_[1];
      nvacc[p] += a.x*a.x + a.y*a.y + a.z*a.z + a.w*a.w
                + bq.x*bq.x + bq.y*bq.y + bq.z*bq.z + bq.w*bq.w;
      union { bf16x8 v8; __hip_bfloat162 h[4]; } u;
      u.h[0] = __float22bfloat162_rn(make_float2(a.x, a.y));
      u.h[1] = __float22bfloat162_rn(make_float2(a.z, a.w));
      u.h[2] = __float22bfloat162_rn(make_float2(bq.x, bq.y));
      u.h[3] = __float22bfloat162_rn(make_float2(bq.z, bq.w));
      *(bf16x8*)((char*)lv + off) = u.v8;

      const float4* sl_ = (const float4*)(lbase + (size_t)row * D_ + kt * BKT + kc * 8);
      float4 c = sl_[0], dq = sl_[1];
      nlacc[p] += c.x*c.x + c.y*c.y + c.z*c.z + c.w*c.w
                + dq.x*dq.x + dq.y*dq.y + dq.z*dq.z + dq.w*dq.w;
      union { bf16x8 v8; __hip_bfloat162 h[4]; } u2;
      u2.h[0] = __float22bfloat162_rn(make_float2(c.x, c.y));
      u2.h[1] = __float22bfloat162_rn(make_float2(c.z, c.w));
      u2.h[2] = __float22bfloat162_rn(make_float2(dq.x, dq.y));
      u2.h[3] = __float22bfloat162_rn(make_float2(dq.z, dq.w));
      *(bf16x8*)((char*)ll + off) = u2.v8;
    }
    __syncthreads();
    // ---- MFMA: 4 k-steps of 32; wave owns 16 v-rows ----
    #pragma unroll
    for (int ks = 0; ks < 4; ks++) {
      bf16x8 afr, bfr[4];
      {
        int row = w * 16 + c15;
        int off = (row * 256 + ks * 64 + g * 16) ^ ((row & 7) << 4);
        afr = *(const bf16x8*)((const char*)lv + off);
      }
      #pragma unroll
      for (int n = 0; n < 4; n++) {
        int row = n * 16 + c15;
        int off = (row * 256 + ks * 64 + g * 16) ^ ((row & 7) << 4);
        bfr[n] = *(const bf16x8*)((const char*)ll + off);
      }
      #pragma unroll
      for (int n = 0; n < 4; n++)
        acc[n] = __builtin_amdgcn_mfma_f32_16x16x32_bf16(afr, bfr[n], acc[n], 0, 0, 0);
    }
    __syncthreads();
  }

  // ---- row-norm reductions (16 consecutive lanes share a staged row) ----
  #pragma unroll
  for (int p = 0; p < 4; p++) {
    float s = nvacc[p];
    s += __shfl_xor(s, 1); s += __shfl_xor(s, 2);
    s += __shfl_xor(s, 4); s += __shfl_xor(s, 8);
    if ((t & 15) == 0) normv_s[p * 16 + (t >> 4)] = s;
    float s2 = nlacc[p];
    s2 += __shfl_xor(s2, 1); s2 += __shfl_xor(s2, 2);
    s2 += __shfl_xor(s2, 4); s2 += __shfl_xor(s2, 8);
    if ((t & 15) == 0) norml_s[p * 16 + (t >> 4)] = s2;
  }
  __syncthreads();

  // ---- epilogue: pd + masking, row/col mins ----
  const float BIG = 3.0e38f;
  float pdv[4][4];   // [n][j]
  #pragma unroll
  for (int n = 0; n < 4; n++)
    #pragma unroll
    for (int j = 0; j < 4; j++) {
      int row = w * 16 + g * 4 + j;
      int col = n * 16 + c15;
      float pd = normv_s[row] + norml_s[col] - 2.0f * acc[n][j];
      bool valid = (mvs[row] != 0.f) && (mls[col] != 0.f);
      pdv[n][j] = valid ? pd : BIG;
    }

  // row mins (over all 64 cols) -> masked sum over this wave's 16 rows
  float svl = 0.f;
  #pragma unroll
  for (int j = 0; j < 4; j++) {
    float rm = fminf(fminf(pdv[0][j], pdv[1][j]),
                     fminf(pdv[2][j], pdv[3][j]));
    rm = fminf(rm, __shfl_xor(rm, 1));
    rm = fminf(rm, __shfl_xor(rm, 2));
    rm = fminf(rm, __shfl_xor(rm, 4));
    rm = fminf(rm, __shfl_xor(rm, 8));
    int row = w * 16 + g * 4 + j;
    if (c15 == 0 && mvs[row] != 0.f) svl += rm;
  }
  svl += __shfl_xor(svl, 16);
  svl += __shfl_xor(svl, 32);
  if (lane == 0) wavesum[w] = svl;

  // col mins over this wave's 16 rows
  #pragma unroll
  for (int n = 0; n < 4; n++) {
    float cm = fminf(fminf(pdv[n][0], pdv[n][1]),
                     fminf(pdv[n][2], pdv[n][3]));
    cm = fminf(cm, __shfl_xor(cm, 16));
    cm = fminf(cm, __shfl_xor(cm, 32));
    if (g == 0) wavecol[w][n * 16 + c15] = cm;
  }
  __syncthreads();

  if (t < TL) {
    float cm = fminf(fminf(wavecol[0][t], wavecol[1][t]),
                     fminf(wavecol[2][t], wavecol[3][t]));
    pcol[((size_t)b * NCHUNK + chunk) * TL + t] = cm;
  }
  if (t == 0)
    psum[(size_t)b * NCHUNK + chunk] = wavesum[0] + wavesum[1] + wavesum[2] + wavesum[3];
}

__global__ __launch_bounds__(64) void chamfer_fin(
    const float* __restrict__ pcol, const float* __restrict__ psum,
    const float* __restrict__ mv, const float* __restrict__ ml,
    float* __restrict__ out)
{
  int b = blockIdx.x;
  int l = threadIdx.x;
  float cm = pcol[((size_t)b * NCHUNK + 0) * 64 + l];
  #pragma unroll
  for (int i = 1; i < NCHUNK; i++)
    cm = fminf(cm, pcol[((size_t)b * NCHUNK + i) * 64 + l]);
  float mlv = ml[(size_t)b * 64 + l];
  float sl = (mlv != 0.f) ? cm : 0.f;
  float nl = mlv;
  float nv = 0.f;
  #pragma unroll
  for (int i = 0; i < 8; i++) nv += mv[(size_t)b * 512 + l * 8 + i];
  float sv = (l < NCHUNK) ? psum[(size_t)b * NCHUNK + l] : 0.f;
  #pragma unroll
  for (int s = 1; s < 64; s <<= 1) {
    sl += __shfl_xor(sl, s);
    nl += __shfl_xor(nl, s);
    nv += __shfl_xor(nv, s);
    sv += __shfl_xor(sv, s);
  }
  if (l == 0) out[b] = sl / nl + sv / nv;
}

extern "C" void kernel_launch(void* const* d_in, const int* in_sizes, int n_in,
                              void* d_out, int out_size, void* d_ws, size_t ws_size,
                              hipStream_t stream) {
  const float* vf = (const float*)d_in[0];
  const float* lf = (const float*)d_in[1];
  const float* mv = (const float*)d_in[2];
  const float* ml = (const float*)d_in[3];
  float* out  = (float*)d_out;
  float* pcol = (float*)d_ws;                       // [128][8][64]
  float* psum = pcol + 128 * NCHUNK * 64;           // [128][8]
  chamfer_main<<<128 * NCHUNK, 256, 0, stream>>>(vf, lf, mv, ml, pcol, psum);
  chamfer_fin<<<128, 64, 0, stream>>>(pcol, psum, mv, ml, out);
}